// Round 1
// baseline (3022.486 us; speedup 1.0000x reference)
//
#include <hip/hip_runtime.h>

// Vanilla RNN: B=64, T=512, I=512, H=1024, O=512.
// Phase 1: xin = x @ W_in + b_in  (bf16 MFMA GEMM, store bf16 to ws)
// Phase 2: persistent recurrence: 4 batch-groups x 16 wgs; W_h register-resident,
//          per-step 16-wg barrier via agent-scope atomics, double-buffered h.
// Phase 3: out = h_final @ W_out + b_out (fp32 vector).

typedef float f32x4 __attribute__((ext_vector_type(4)));
typedef short bf16x8 __attribute__((ext_vector_type(8)));
typedef short s16x4 __attribute__((ext_vector_type(4)));

__device__ __forceinline__ short f2bf(float f) {
  unsigned u = __builtin_bit_cast(unsigned, f);
  u = (u + 0x7FFFu + ((u >> 16) & 1u)) >> 16;   // RNE
  return (short)u;
}
__device__ __forceinline__ float bf2f(short s) {
  unsigned u = ((unsigned)(unsigned short)s) << 16;
  return __builtin_bit_cast(float, u);
}

// ---------------- Phase 1: input projection GEMM --------------------------
// M=32768 (B*T), K=512, N=1024. 128x128 tile, BK=32, 4 waves.
__global__ __launch_bounds__(256) void k_inproj(const float* __restrict__ X,
                                                const float* __restrict__ Win,
                                                const float* __restrict__ bin,
                                                short* __restrict__ xin) {
  __shared__ __align__(16) short Al[128][40];   // +8 pad: bank spread, 16B-aligned rows
  __shared__ __align__(16) short Bl[128][40];   // stored [n][k]
  __shared__ __align__(16) short Cl[128][64];   // epilogue restage (half tile)
  const int m0g = blockIdx.x * 128, n0g = blockIdx.y * 128;
  const int tid = threadIdx.x;
  const int lane = tid & 63, wave = tid >> 6;
  const int wm = (wave & 1) * 64, wn = (wave >> 1) * 64;
  const int l15 = lane & 15, lhi = lane >> 4;

  f32x4 acc[4][4] = {};

  for (int kb = 0; kb < 512; kb += 32) {
    // stage A: x[m0g..+128][kb..+32] fp32 -> bf16
    #pragma unroll
    for (int i = 0; i < 4; ++i) {
      int flat = tid + i * 256;              // 0..1023
      int row = flat >> 3, k4 = (flat & 7) * 4;
      float4 v = *(const float4*)(X + (size_t)(m0g + row) * 512 + kb + k4);
      s16x4 s; s[0] = f2bf(v.x); s[1] = f2bf(v.y); s[2] = f2bf(v.z); s[3] = f2bf(v.w);
      *(s16x4*)&Al[row][k4] = s;
    }
    // stage B transposed: W_in[kb+k][n] -> Bl[n][k]; 4 coalesced dword loads/thread
    #pragma unroll
    for (int i = 0; i < 4; ++i) {
      int flat = tid + i * 256;
      int n = flat & 127, k0 = (flat >> 7) * 4;
      const float* wp = Win + (size_t)(kb + k0) * 1024 + n0g + n;
      s16x4 s;
      s[0] = f2bf(wp[0]); s[1] = f2bf(wp[1024]); s[2] = f2bf(wp[2048]); s[3] = f2bf(wp[3072]);
      *(s16x4*)&Bl[n][k0] = s;
    }
    __syncthreads();
    bf16x8 a[4], b[4];
    #pragma unroll
    for (int mt = 0; mt < 4; ++mt) a[mt] = *(const bf16x8*)&Al[wm + mt * 16 + l15][lhi * 8];
    #pragma unroll
    for (int nt = 0; nt < 4; ++nt) b[nt] = *(const bf16x8*)&Bl[wn + nt * 16 + l15][lhi * 8];
    #pragma unroll
    for (int mt = 0; mt < 4; ++mt)
      #pragma unroll
      for (int nt = 0; nt < 4; ++nt)
        acc[mt][nt] = __builtin_amdgcn_mfma_f32_16x16x32_bf16(a[mt], b[nt], acc[mt][nt], 0, 0, 0);
    __syncthreads();
  }

  float bias[4];
  #pragma unroll
  for (int nt = 0; nt < 4; ++nt) bias[nt] = bin[n0g + wn + nt * 16 + l15];

  // epilogue: restage through LDS in two 64-col halves for coalesced stores
  #pragma unroll
  for (int h = 0; h < 2; ++h) {
    if ((wave >> 1) == h) {
      #pragma unroll
      for (int mt = 0; mt < 4; ++mt)
        #pragma unroll
        for (int nt = 0; nt < 4; ++nt)
          #pragma unroll
          for (int r = 0; r < 4; ++r) {
            int row = wm + mt * 16 + lhi * 4 + r;
            Cl[row][nt * 16 + l15] = f2bf(acc[mt][nt][r] + bias[nt]);
          }
    }
    __syncthreads();
    {
      int row = tid >> 1, c0 = (tid & 1) * 32;
      const int4* src = (const int4*)&Cl[row][c0];
      int4* dst = (int4*)(xin + (size_t)(m0g + row) * 1024 + n0g + h * 64 + c0);
      dst[0] = src[0]; dst[1] = src[1]; dst[2] = src[2]; dst[3] = src[3];
    }
    __syncthreads();
  }
}

// ---------------- Phase 2: persistent recurrence --------------------------
// 64 wgs x 256 thr. group g = wg>>4 (16 batch rows), cj = wg&15 (64 hidden cols).
// W_h slice register-resident: per wave 8(kt) x 4(nt) bf16x8 = 128 VGPRs.
__global__ __launch_bounds__(256) void k_recur(const short* __restrict__ xin,
                                               const float* __restrict__ Wh,
                                               const float* __restrict__ bh,
                                               short* __restrict__ hbuf,
                                               float* __restrict__ hfin,
                                               int* __restrict__ cnt) {
  const int wg = blockIdx.x;
  const int g = wg >> 4, cj = wg & 15;
  const int tid = threadIdx.x, lane = tid & 63, wave = tid >> 6;
  const int l15 = lane & 15, lhi = lane >> 4;
  const int colbase = cj << 6, rowbase = g << 4;
  __shared__ __align__(16) float part[4][16][68];   // K-split partials (+4 pad)

  // one-time W_h gather -> registers (coalesced 64B per quarter-wave)
  bf16x8 wf[8][4];
  {
    const float* wp = Wh + (size_t)(wave * 256 + lhi * 8) * 1024 + colbase + l15;
    #pragma unroll
    for (int kt = 0; kt < 8; ++kt)
      #pragma unroll
      for (int nt = 0; nt < 4; ++nt) {
        bf16x8 tmp;
        #pragma unroll
        for (int j = 0; j < 8; ++j)
          tmp[j] = f2bf(wp[(size_t)(kt * 32 + j) * 1024 + nt * 16]);
        wf[kt][nt] = tmp;
      }
  }

  const int erow = tid >> 4, ec0 = (tid & 15) << 2;  // epilogue: row 0..15, 4 cols
  const float4 bh4 = *(const float4*)(bh + colbase + ec0);
  int* cg = cnt + (g << 6);                          // 256B-spaced counters
  const short* xrow = xin + (size_t)(rowbase + erow) * 512 * 1024 + colbase + ec0;

  for (int t = 0; t < 512; ++t) {
    s16x4 xs = *(const s16x4*)(xrow + (size_t)t * 1024);   // prefetch xin_t early
    f32x4 acc[4] = {};
    if (t > 0) {
      const short* hs = hbuf + ((t & 1) << 16) + (rowbase + l15) * 1024 + (wave << 8) + lhi * 8;
      bf16x8 af[8];
      #pragma unroll
      for (int kt = 0; kt < 8; ++kt) af[kt] = *(const bf16x8*)(hs + kt * 32);
      #pragma unroll
      for (int kt = 0; kt < 8; ++kt)
        #pragma unroll
        for (int nt = 0; nt < 4; ++nt)
          acc[nt] = __builtin_amdgcn_mfma_f32_16x16x32_bf16(af[kt], wf[kt][nt], acc[nt], 0, 0, 0);
    }
    #pragma unroll
    for (int nt = 0; nt < 4; ++nt)
      #pragma unroll
      for (int r = 0; r < 4; ++r)
        part[wave][lhi * 4 + r][nt * 16 + l15] = acc[nt][r];
    __syncthreads();

    f32x4 p0 = *(const f32x4*)&part[0][erow][ec0];
    f32x4 p1 = *(const f32x4*)&part[1][erow][ec0];
    f32x4 p2 = *(const f32x4*)&part[2][erow][ec0];
    f32x4 p3 = *(const f32x4*)&part[3][erow][ec0];
    f32x4 ps = (p0 + p1) + (p2 + p3);
    float h0 = tanhf(ps[0] + bh4.x + bf2f(xs[0]));
    float h1 = tanhf(ps[1] + bh4.y + bf2f(xs[1]));
    float h2 = tanhf(ps[2] + bh4.z + bf2f(xs[2]));
    float h3 = tanhf(ps[3] + bh4.w + bf2f(xs[3]));
    s16x4 hb; hb[0] = f2bf(h0); hb[1] = f2bf(h1); hb[2] = f2bf(h2); hb[3] = f2bf(h3);
    *(s16x4*)(hbuf + (((t + 1) & 1) << 16) + (rowbase + erow) * 1024 + colbase + ec0) = hb;
    if (t == 511) {
      float4 hf4; hf4.x = h0; hf4.y = h1; hf4.z = h2; hf4.w = h3;
      *(float4*)(hfin + (rowbase + erow) * 1024 + colbase + ec0) = hf4;
    }
    __syncthreads();   // part reusable + all global h stores drained per-wave

    if (t < 511) {     // 16-wg group barrier (agent scope, cross-XCD safe)
      if (tid == 0) {
        __threadfence();   // release: flush h stores to coherence point
        __hip_atomic_fetch_add(cg, 1, __ATOMIC_RELAXED, __HIP_MEMORY_SCOPE_AGENT);
        const int target = (t + 1) << 4;
        while (__hip_atomic_load(cg, __ATOMIC_RELAXED, __HIP_MEMORY_SCOPE_AGENT) < target) {}
        (void)__hip_atomic_load(cg, __ATOMIC_ACQUIRE, __HIP_MEMORY_SCOPE_AGENT); // inv L1/L2
      }
      __syncthreads();
    }
  }
}

// ---------------- Phase 3: output projection ------------------------------
__global__ __launch_bounds__(256) void k_out(const float* __restrict__ hfin,
                                             const float* __restrict__ Wout,
                                             const float* __restrict__ bout,
                                             float* __restrict__ out) {
  __shared__ __align__(16) float hrow[1024];
  const int b = blockIdx.x >> 1;
  const int c0 = (blockIdx.x & 1) << 8;
  const int tid = threadIdx.x;
  #pragma unroll
  for (int i = 0; i < 4; ++i) hrow[tid + i * 256] = hfin[b * 1024 + tid + i * 256];
  __syncthreads();
  const int col = c0 + tid;
  const float* wp = Wout + col;
  float a0 = bout[col], a1 = 0, a2 = 0, a3 = 0, a4 = 0, a5 = 0, a6 = 0, a7 = 0;
  #pragma unroll 4
  for (int k = 0; k < 1024; k += 8) {
    a0 += hrow[k + 0] * wp[(size_t)(k + 0) * 512];
    a1 += hrow[k + 1] * wp[(size_t)(k + 1) * 512];
    a2 += hrow[k + 2] * wp[(size_t)(k + 2) * 512];
    a3 += hrow[k + 3] * wp[(size_t)(k + 3) * 512];
    a4 += hrow[k + 4] * wp[(size_t)(k + 4) * 512];
    a5 += hrow[k + 5] * wp[(size_t)(k + 5) * 512];
    a6 += hrow[k + 6] * wp[(size_t)(k + 6) * 512];
    a7 += hrow[k + 7] * wp[(size_t)(k + 7) * 512];
  }
  out[b * 512 + col] = ((a0 + a1) + (a2 + a3)) + ((a4 + a5) + (a6 + a7));
}

// ---------------- launch --------------------------------------------------
extern "C" void kernel_launch(void* const* d_in, const int* in_sizes, int n_in,
                              void* d_out, int out_size, void* d_ws, size_t ws_size,
                              hipStream_t stream) {
  const float* x    = (const float*)d_in[0];
  const float* Win  = (const float*)d_in[1];
  const float* bin  = (const float*)d_in[2];
  const float* Wh   = (const float*)d_in[3];
  const float* bh   = (const float*)d_in[4];
  const float* Wout = (const float*)d_in[5];
  const float* bout = (const float*)d_in[6];

  char* ws = (char*)d_ws;
  short* xin  = (short*)ws;                    // 64*512*1024 bf16 = 67,108,864 B
  short* hbuf = (short*)(ws + 67108864);       // 2 x 64*1024 bf16 = 262,144 B
  float* hfin = (float*)(ws + 67371008);       // 64*1024 f32      = 262,144 B
  int*   cnt  = (int*)(ws + 67633152);         // 4 counters, 256B spaced

  hipMemsetAsync(cnt, 0, 1024, stream);        // deterministic barrier state per call
  hipLaunchKernelGGL(k_inproj, dim3(256, 8), dim3(256), 0, stream, x, Win, bin, xin);
  hipLaunchKernelGGL(k_recur, dim3(64), dim3(256), 0, stream, xin, Wh, bh, hbuf, hfin, cnt);
  hipLaunchKernelGGL(k_out, dim3(128), dim3(256), 0, stream, hfin, Wout, bout, (float*)d_out);
}